// Round 6
// baseline (1222.268 us; speedup 1.0000x reference)
//
#include <hip/hip_runtime.h>

// 2-layer GCN, CSR-free edge-parallel design:
//   staging = edges counting-sorted into 256-node buckets (dense stores only)
//   dinv[n] from per-bucket LDS count; ag1[n] = bf16(emb[x_ids[n]]*dinv[n])
//   k_agg1t1: per-bucket LDS acc <- self + edge gathers of ag1;
//             epilogue: y1g = bf16(relu((dinv*acc)@W1+b1)*dinv), 2 planes
//   k_agg2p (x2 planes): LDS acc <- self + edge gathers of y1p;
//             epilogue: s2 row = dinv*acc, pooled per graph -> atomicAdd P
//   k_final: out[g] = P[g]@W2 + cnt[g]*b2
//
// Lessons applied: no global atomics on hot counters (R2), no scattered 4B
// global stores (R1), no single-block serial stages (R4), grid >= 256 blocks
// and no per-node degree divergence (R5: k_build 13% occupancy, 4x write amp).

constexpr int BLK = 256;
constexpr int EPB = 16384;         // edges per hist/scatter block
constexpr int BSH = 8;             // 256 nodes per bucket
constexpr int BKTN = 1 << BSH;     // 256
constexpr int ACCS = 17;           // padded LDS acc stride (bank-decorrelated)

__device__ inline unsigned short f2bf(float x) {
  unsigned u = __float_as_uint(x);
  u += 0x7FFF + ((u >> 16) & 1);   // round-to-nearest-even
  return (unsigned short)(u >> 16);
}
__device__ inline float bf2f(unsigned short h) {
  return __uint_as_float((unsigned)h << 16);
}
__device__ inline unsigned pk(float a, float b) {
  return (unsigned)f2bf(a) | ((unsigned)f2bf(b) << 16);
}

// per-block LDS histogram of col buckets
__global__ __launch_bounds__(BLK) void k_hist(const int* __restrict__ col, int E,
                                              int nbkt, int nblk,
                                              int* __restrict__ hist) {
  __shared__ int h[512];
  int tid = threadIdx.x, blk = blockIdx.x;
  for (int i = tid; i < nbkt; i += BLK) h[i] = 0;
  __syncthreads();
  int e0 = blk * EPB, e1 = min(E, e0 + EPB);
  for (int e = e0 + tid; e < e1; e += BLK) atomicAdd(&h[col[e] >> BSH], 1);
  __syncthreads();
  for (int b = tid; b < nbkt; b += BLK) hist[b * nblk + blk] = h[b];
}

// multi-block scan, stage 1: block-local exclusive scan + block sums
__global__ __launch_bounds__(1024) void k_scan_a(const int* __restrict__ hist, int tot,
                                                 int* __restrict__ off,
                                                 int* __restrict__ bsums) {
  __shared__ int sd[1024];
  int tid = threadIdx.x;
  int i = blockIdx.x * 1024 + tid;
  int v = (i < tot) ? hist[i] : 0;
  sd[tid] = v;
  __syncthreads();
  for (int o = 1; o < 1024; o <<= 1) {
    int u = (tid >= o) ? sd[tid - o] : 0;
    __syncthreads();
    sd[tid] += u;
    __syncthreads();
  }
  if (i < tot) off[i] = sd[tid] - v;  // block-local exclusive
  if (tid == 1023) bsums[blockIdx.x] = sd[tid];
}

// stage 2: add prefix of block sums; derive bucket segment starts
__global__ __launch_bounds__(1024) void k_scan_c(int tot, int nblk, int nbkt, int E,
                                                 const int* __restrict__ bsums,
                                                 int* __restrict__ off,
                                                 int* __restrict__ bucket_off) {
  __shared__ int sbase;
  int tid = threadIdx.x, b = blockIdx.x;
  if (tid == 0) {
    int s = 0;
    for (int j = 0; j < b; ++j) s += bsums[j];
    sbase = s;
  }
  __syncthreads();
  int i = b * 1024 + tid;
  if (i < tot) {
    int v = off[i] + sbase;
    off[i] = v;
    if (i % nblk == 0) bucket_off[i / nblk] = v;
  }
  if (i == 0) bucket_off[nbkt] = E;
}

// scatter packed edges into bucket-major segments; stores dense per block
__global__ __launch_bounds__(BLK) void k_scatter(const int* __restrict__ row,
                                                 const int* __restrict__ col, int E,
                                                 int nbkt, int nblk,
                                                 const int* __restrict__ off,
                                                 int* __restrict__ staging) {
  __shared__ int base[512];
  __shared__ int cur[512];
  int tid = threadIdx.x, blk = blockIdx.x;
  for (int b = tid; b < nbkt; b += BLK) {
    base[b] = off[b * nblk + blk];
    cur[b] = 0;
  }
  __syncthreads();
  int e0 = blk * EPB, e1 = min(E, e0 + EPB);
  for (int e = e0 + tid; e < e1; e += BLK) {
    int c = col[e];
    int b = c >> BSH;
    int rk = atomicAdd(&cur[b], 1);
    staging[base[b] + rk] = (row[e] << BSH) | (c & (BKTN - 1));
  }
}

// per-bucket degree -> dinv; fused embedding prep: ag1 = bf16(emb[id]*dinv)
__global__ __launch_bounds__(BLK) void k_degprep(const int* __restrict__ staging,
                                                 const int* __restrict__ bucket_off,
                                                 const int* __restrict__ x_ids,
                                                 const float* __restrict__ emb,
                                                 int N,
                                                 float* __restrict__ dinv,
                                                 unsigned short* __restrict__ ag1) {
  __shared__ int cnt[BKTN];
  int tid = threadIdx.x, b = blockIdx.x;
  int beg = bucket_off[b], end = bucket_off[b + 1];
  cnt[tid] = 0;
  __syncthreads();
  for (int i = beg + tid; i < end; i += BLK)
    atomicAdd(&cnt[staging[i] & (BKTN - 1)], 1);
  __syncthreads();
  int node = (b << BSH) + tid;
  if (node >= N) return;
  float d = rsqrtf((float)(cnt[tid] + 1));  // +1 self-loop
  dinv[node] = d;
  const float* er = emb + (size_t)x_ids[node] * 16;
  float4 e0 = *(const float4*)(er);
  float4 e1 = *(const float4*)(er + 4);
  float4 e2 = *(const float4*)(er + 8);
  float4 e3 = *(const float4*)(er + 12);
  uint4 o0, o1;
  o0.x = pk(e0.x * d, e0.y * d); o0.y = pk(e0.z * d, e0.w * d);
  o0.z = pk(e1.x * d, e1.y * d); o0.w = pk(e1.z * d, e1.w * d);
  o1.x = pk(e2.x * d, e2.y * d); o1.y = pk(e2.z * d, e2.w * d);
  o1.z = pk(e3.x * d, e3.y * d); o1.w = pk(e3.z * d, e3.w * d);
  *(uint4*)(ag1 + (size_t)node * 16) = o0;
  *(uint4*)(ag1 + (size_t)node * 16 + 8) = o1;
}

// edge-parallel layer-1 aggregation + fused 16->32 GEMV/ReLU epilogue
__global__ __launch_bounds__(BLK) void k_agg1t1(const unsigned short* __restrict__ ag1,
                                                const int* __restrict__ staging,
                                                const int* __restrict__ bucket_off,
                                                const float* __restrict__ dinv,
                                                const float* __restrict__ W1,
                                                const float* __restrict__ b1, int N,
                                                unsigned short* __restrict__ y1g) {
  __shared__ float acc[BKTN * ACCS];
  __shared__ float W[512];
  __shared__ float bb[32];
  int tid = threadIdx.x, b = blockIdx.x;
  for (int i = tid; i < 512; i += BLK) W[i] = W1[i];
  if (tid < 32) bb[tid] = b1[tid];
  int node = (b << BSH) + tid;
  if (node < N) {
    uint4 v0 = *(const uint4*)(ag1 + (size_t)node * 16);
    uint4 v1 = *(const uint4*)(ag1 + (size_t)node * 16 + 8);
    float* a = acc + tid * ACCS;
    a[0] = bf2f(v0.x & 0xFFFF); a[1] = bf2f(v0.x >> 16);
    a[2] = bf2f(v0.y & 0xFFFF); a[3] = bf2f(v0.y >> 16);
    a[4] = bf2f(v0.z & 0xFFFF); a[5] = bf2f(v0.z >> 16);
    a[6] = bf2f(v0.w & 0xFFFF); a[7] = bf2f(v0.w >> 16);
    a[8] = bf2f(v1.x & 0xFFFF); a[9] = bf2f(v1.x >> 16);
    a[10] = bf2f(v1.y & 0xFFFF); a[11] = bf2f(v1.y >> 16);
    a[12] = bf2f(v1.z & 0xFFFF); a[13] = bf2f(v1.z >> 16);
    a[14] = bf2f(v1.w & 0xFFFF); a[15] = bf2f(v1.w >> 16);
  }
  __syncthreads();
  int beg = bucket_off[b], end = bucket_off[b + 1];
  int ch = tid & 3;
  for (int i0 = beg; i0 < end; i0 += 64) {
    int i = i0 + (tid >> 2);
    if (i < end) {
      int p = staging[i];          // broadcast across the 4 lanes of an edge
      int r = p >> BSH, cl = p & (BKTN - 1);
      uint2 v = *(const uint2*)(ag1 + (size_t)r * 16 + ch * 4);
      float* a = acc + cl * ACCS + ch * 4;
      atomicAdd(a + 0, bf2f(v.x & 0xFFFF));
      atomicAdd(a + 1, bf2f(v.x >> 16));
      atomicAdd(a + 2, bf2f(v.y & 0xFFFF));
      atomicAdd(a + 3, bf2f(v.y >> 16));
    }
  }
  __syncthreads();
  if (node >= N) return;
  float d = dinv[node];
  float x[16];
#pragma unroll
  for (int k = 0; k < 16; ++k) x[k] = acc[tid * ACCS + k] * d;
  float a[32];
#pragma unroll
  for (int j = 0; j < 32; ++j) a[j] = bb[j];
#pragma unroll
  for (int k = 0; k < 16; ++k) {
    float xv = x[k];
#pragma unroll
    for (int j = 0; j < 32; ++j) a[j] += xv * W[k * 32 + j];
  }
#pragma unroll
  for (int j = 0; j < 32; ++j) a[j] = fmaxf(a[j], 0.f) * d;
  uint4 o0 = {pk(a[0], a[1]), pk(a[2], a[3]), pk(a[4], a[5]), pk(a[6], a[7])};
  uint4 o1 = {pk(a[8], a[9]), pk(a[10], a[11]), pk(a[12], a[13]), pk(a[14], a[15])};
  uint4 o2 = {pk(a[16], a[17]), pk(a[18], a[19]), pk(a[20], a[21]), pk(a[22], a[23])};
  uint4 o3 = {pk(a[24], a[25]), pk(a[26], a[27]), pk(a[28], a[29]), pk(a[30], a[31])};
  unsigned short* y0 = y1g + (size_t)node * 16;
  unsigned short* y1 = y1g + (size_t)N * 16 + (size_t)node * 16;
  *(uint4*)(y0) = o0;
  *(uint4*)(y0 + 8) = o1;
  *(uint4*)(y1) = o2;
  *(uint4*)(y1 + 8) = o3;
}

// edge-parallel layer-2 aggregation (one 16-feat plane) + fused graph pooling
__global__ __launch_bounds__(BLK) void k_agg2p(const unsigned short* __restrict__ y1p,
                                               const int* __restrict__ staging,
                                               const int* __restrict__ bucket_off,
                                               const float* __restrict__ dinv,
                                               const int* __restrict__ batch, int N,
                                               int pofs, float* __restrict__ P) {
  __shared__ float acc[BKTN * ACCS];
  __shared__ float partial[32 * 16];
  __shared__ int gs[2];
  int tid = threadIdx.x, b = blockIdx.x;
  int base = b << BSH;
  if (tid == 0) gs[0] = batch[base];
  if (tid == 1) gs[1] = batch[min(base + BKTN - 1, N - 1)];
  int node = base + tid;
  if (node < N) {
    uint4 v0 = *(const uint4*)(y1p + (size_t)node * 16);
    uint4 v1 = *(const uint4*)(y1p + (size_t)node * 16 + 8);
    float* a = acc + tid * ACCS;
    a[0] = bf2f(v0.x & 0xFFFF); a[1] = bf2f(v0.x >> 16);
    a[2] = bf2f(v0.y & 0xFFFF); a[3] = bf2f(v0.y >> 16);
    a[4] = bf2f(v0.z & 0xFFFF); a[5] = bf2f(v0.z >> 16);
    a[6] = bf2f(v0.w & 0xFFFF); a[7] = bf2f(v0.w >> 16);
    a[8] = bf2f(v1.x & 0xFFFF); a[9] = bf2f(v1.x >> 16);
    a[10] = bf2f(v1.y & 0xFFFF); a[11] = bf2f(v1.y >> 16);
    a[12] = bf2f(v1.z & 0xFFFF); a[13] = bf2f(v1.z >> 16);
    a[14] = bf2f(v1.w & 0xFFFF); a[15] = bf2f(v1.w >> 16);
  }
  __syncthreads();
  int beg = bucket_off[b], end = bucket_off[b + 1];
  int ch = tid & 3;
  for (int i0 = beg; i0 < end; i0 += 64) {
    int i = i0 + (tid >> 2);
    if (i < end) {
      int p = staging[i];
      int r = p >> BSH, cl = p & (BKTN - 1);
      uint2 v = *(const uint2*)(y1p + (size_t)r * 16 + ch * 4);
      float* a = acc + cl * ACCS + ch * 4;
      atomicAdd(a + 0, bf2f(v.x & 0xFFFF));
      atomicAdd(a + 1, bf2f(v.x >> 16));
      atomicAdd(a + 2, bf2f(v.y & 0xFFFF));
      atomicAdd(a + 3, bf2f(v.y >> 16));
    }
  }
  __syncthreads();
  float v[16];
  int myg = -1;
  if (node < N) {
    float d = dinv[node];
#pragma unroll
    for (int k = 0; k < 16; ++k) v[k] = acc[tid * ACCS + k] * d;
    myg = batch[node];
  }
  int g0 = gs[0], g1 = gs[1];
  for (int clo = g0; clo <= g1; clo += 32) {
    for (int j = tid; j < 512; j += BLK) partial[j] = 0.f;
    __syncthreads();
    if (myg >= clo && myg < clo + 32) {
      float* pp = partial + (myg - clo) * 16;
#pragma unroll
      for (int k = 0; k < 16; ++k) atomicAdd(pp + k, v[k]);
    }
    __syncthreads();
    int ng = min(32, g1 - clo + 1);
    for (int j = tid; j < ng * 16; j += BLK)
      atomicAdd(P + (size_t)(clo + (j >> 4)) * 32 + pofs + (j & 15), partial[j]);
    __syncthreads();
  }
}

// out[g] = P[g] @ W2 + cnt[g]*b2; cnt via binary search on sorted batch
__global__ __launch_bounds__(64) void k_final(const float* __restrict__ P,
                                              const int* __restrict__ batch, int N,
                                              const float* __restrict__ W2,
                                              const float* __restrict__ b2,
                                              float* __restrict__ out) {
  __shared__ float pr[32];
  __shared__ int se[2];
  int g = blockIdx.x, tid = threadIdx.x;
  if (tid < 2) {
    int v = g + tid;
    int lo = 0, hi = N;
    while (lo < hi) {
      int mid = (lo + hi) >> 1;
      if (batch[mid] < v) lo = mid + 1; else hi = mid;
    }
    se[tid] = lo;
  }
  if (tid < 32) pr[tid] = P[(size_t)g * 32 + tid];
  __syncthreads();
  if (tid < 41) {
    float o = (float)(se[1] - se[0]) * b2[tid];
#pragma unroll
    for (int k = 0; k < 32; ++k) o += pr[k] * W2[k * 41 + tid];
    out[(size_t)g * 41 + tid] = o;
  }
}

extern "C" void kernel_launch(void* const* d_in, const int* in_sizes, int n_in,
                              void* d_out, int out_size, void* d_ws, size_t ws_size,
                              hipStream_t stream) {
  const int* x_ids = (const int*)d_in[0];
  const int* edge_index = (const int*)d_in[1];
  const int* batch = (const int*)d_in[2];
  const float* emb = (const float*)d_in[3];
  const float* W1 = (const float*)d_in[4];
  const float* b1 = (const float*)d_in[5];
  const float* W2 = (const float*)d_in[6];
  const float* b2 = (const float*)d_in[7];
  float* out = (float*)d_out;

  const int N = in_sizes[0];
  const int E = in_sizes[1] / 2;
  const int G = out_size / 41;
  const int* row = edge_index;
  const int* col = edge_index + E;

  const int nbkt = (N + BKTN - 1) >> BSH;       // 391
  const int nblk = (E + EPB - 1) / EPB;         // 196
  const int tot = nbkt * nblk;                  // ~76.6K
  const int nscan = (tot + 1023) >> 10;

  char* ws = (char*)d_ws;
  size_t woff = 0;
  auto alloc = [&](size_t bytes) -> char* {
    char* p = ws + woff;
    woff += (bytes + 255) & ~(size_t)255;
    return p;
  };
  int* staging = (int*)alloc((size_t)E * 4);
  float* dinv = (float*)alloc((size_t)N * 4);
  unsigned short* ag1 = (unsigned short*)alloc((size_t)N * 16 * 2);
  unsigned short* y1g = (unsigned short*)alloc((size_t)N * 32 * 2);
  int* hist = (int*)alloc((size_t)tot * 4);
  int* off = (int*)alloc((size_t)tot * 4);
  int* bucket_off = (int*)alloc(((size_t)nbkt + 1) * 4);
  int* bsums = (int*)alloc((size_t)nscan * 4);
  float* P = (float*)alloc((size_t)G * 32 * 4);
  (void)ws_size; (void)n_in;

  hipMemsetAsync(P, 0, (size_t)G * 32 * 4, stream);

  k_hist<<<nblk, BLK, 0, stream>>>(col, E, nbkt, nblk, hist);
  k_scan_a<<<nscan, 1024, 0, stream>>>(hist, tot, off, bsums);
  k_scan_c<<<nscan, 1024, 0, stream>>>(tot, nblk, nbkt, E, bsums, off, bucket_off);
  k_scatter<<<nblk, BLK, 0, stream>>>(row, col, E, nbkt, nblk, off, staging);
  k_degprep<<<nbkt, BLK, 0, stream>>>(staging, bucket_off, x_ids, emb, N, dinv, ag1);
  k_agg1t1<<<nbkt, BLK, 0, stream>>>(ag1, staging, bucket_off, dinv, W1, b1, N, y1g);
  k_agg2p<<<nbkt, BLK, 0, stream>>>(y1g, staging, bucket_off, dinv, batch, N, 0, P);
  k_agg2p<<<nbkt, BLK, 0, stream>>>(y1g + (size_t)N * 16, staging, bucket_off, dinv,
                                    batch, N, 16, P);
  k_final<<<G, 64, 0, stream>>>(P, batch, N, W2, b2, out);
}

// Round 7
// 253.403 us; speedup vs baseline: 4.8234x; 4.8234x over previous
//
#include <hip/hip_runtime.h>

// 2-layer GCN, bucketed counting sort + LDS-local CSR + register aggregation:
//   staging = edges sorted into 256-node buckets (dense global stores only)
//   k_degprep: per-bucket degree -> dinv; ag1 = bf16(emb[x_ids]*dinv)
//   k_fuse1:  per-bucket LDS CSR rebuild; 2 lanes/node gather ag1 rows into
//             registers; shfl-exchange halves; fused 16->32 GEMV+ReLU;
//             y1g written as 2 bf16 planes (3.2MB each, L2-resident)
//   k_fuse2:  (x2 planes) LDS CSR rebuild; register aggregation; s2 f32
//   k_pool:   sorted-batch pooling + 32->41 GEMV
//
// Lessons: R1/R2 no scattered 4B stores / no hot global atomics; R4 no
// single-block stages; R5 k_build's global edge_row fill had 4x write amp +
// 13% occupancy -> CSR now lives only in LDS; R6 edge-parallel LDS-atomic
// accumulation starved the machine -> per-node REGISTER accumulation only.

constexpr int BLK = 256;
constexpr int EPB = 8192;          // edges per hist/scatter block
constexpr int BSH = 8;             // 256 nodes per bucket
constexpr int BKTN = 1 << BSH;     // 256
constexpr int CAP = 10240;         // LDS edge-list capacity (chunked if over)

__device__ inline unsigned short f2bf(float x) {
  unsigned u = __float_as_uint(x);
  u += 0x7FFF + ((u >> 16) & 1);   // round-to-nearest-even
  return (unsigned short)(u >> 16);
}
__device__ inline float bf2f(unsigned short h) {
  return __uint_as_float((unsigned)h << 16);
}
__device__ inline unsigned pk(float a, float b) {
  return (unsigned)f2bf(a) | ((unsigned)f2bf(b) << 16);
}

// per-block LDS histogram of col buckets
__global__ __launch_bounds__(BLK) void k_hist(const int* __restrict__ col, int E,
                                              int nbkt, int nblk,
                                              int* __restrict__ hist) {
  __shared__ int h[512];
  int tid = threadIdx.x, blk = blockIdx.x;
  for (int i = tid; i < nbkt; i += BLK) h[i] = 0;
  __syncthreads();
  int e0 = blk * EPB, e1 = min(E, e0 + EPB);
  for (int e = e0 + tid; e < e1; e += BLK) atomicAdd(&h[col[e] >> BSH], 1);
  __syncthreads();
  for (int b = tid; b < nbkt; b += BLK) hist[b * nblk + blk] = h[b];
}

// multi-block scan, stage 1: block-local exclusive scan + block sums
__global__ __launch_bounds__(1024) void k_scan_a(const int* __restrict__ hist, int tot,
                                                 int* __restrict__ off,
                                                 int* __restrict__ bsums) {
  __shared__ int sd[1024];
  int tid = threadIdx.x;
  int i = blockIdx.x * 1024 + tid;
  int v = (i < tot) ? hist[i] : 0;
  sd[tid] = v;
  __syncthreads();
  for (int o = 1; o < 1024; o <<= 1) {
    int u = (tid >= o) ? sd[tid - o] : 0;
    __syncthreads();
    sd[tid] += u;
    __syncthreads();
  }
  if (i < tot) off[i] = sd[tid] - v;  // block-local exclusive
  if (tid == 1023) bsums[blockIdx.x] = sd[tid];
}

// stage 2: add prefix of block sums (tree-reduced, R4/R7 lesson: no serial
// dependent-load chains); derive bucket segment starts
__global__ __launch_bounds__(1024) void k_scan_c(int tot, int nblk, int nbkt, int E,
                                                 int nscan,
                                                 const int* __restrict__ bsums,
                                                 int* __restrict__ off,
                                                 int* __restrict__ bucket_off) {
  __shared__ int sd[1024];
  int tid = threadIdx.x, b = blockIdx.x;
  sd[tid] = (tid < b && tid < nscan) ? bsums[tid] : 0;
  __syncthreads();
  for (int o = 512; o >= 1; o >>= 1) {
    if (tid < o) sd[tid] += sd[tid + o];
    __syncthreads();
  }
  int sbase = sd[0];
  int i = b * 1024 + tid;
  if (i < tot) {
    int v = off[i] + sbase;
    off[i] = v;
    if (i % nblk == 0) bucket_off[i / nblk] = v;
  }
  if (i == 0) bucket_off[nbkt] = E;
}

// scatter packed edges into bucket-major segments; stores dense per block
__global__ __launch_bounds__(BLK) void k_scatter(const int* __restrict__ row,
                                                 const int* __restrict__ col, int E,
                                                 int nbkt, int nblk,
                                                 const int* __restrict__ off,
                                                 int* __restrict__ staging) {
  __shared__ int base[512];
  __shared__ int cur[512];
  int tid = threadIdx.x, blk = blockIdx.x;
  for (int b = tid; b < nbkt; b += BLK) {
    base[b] = off[b * nblk + blk];
    cur[b] = 0;
  }
  __syncthreads();
  int e0 = blk * EPB, e1 = min(E, e0 + EPB);
  for (int e = e0 + tid; e < e1; e += BLK) {
    int c = col[e];
    int b = c >> BSH;
    int rk = atomicAdd(&cur[b], 1);
    staging[base[b] + rk] = (row[e] << BSH) | (c & (BKTN - 1));
  }
}

// per-bucket degree -> dinv; fused embedding prep: ag1 = bf16(emb[id]*dinv)
__global__ __launch_bounds__(BLK) void k_degprep(const int* __restrict__ staging,
                                                 const int* __restrict__ bucket_off,
                                                 const int* __restrict__ x_ids,
                                                 const float* __restrict__ emb,
                                                 int N,
                                                 float* __restrict__ dinv,
                                                 unsigned short* __restrict__ ag1) {
  __shared__ int cnt[BKTN];
  int tid = threadIdx.x, b = blockIdx.x;
  int beg = bucket_off[b], end = bucket_off[b + 1];
  cnt[tid] = 0;
  __syncthreads();
  for (int i = beg + tid; i < end; i += BLK)
    atomicAdd(&cnt[staging[i] & (BKTN - 1)], 1);
  __syncthreads();
  int node = (b << BSH) + tid;
  if (node >= N) return;
  float d = rsqrtf((float)(cnt[tid] + 1));  // +1 self-loop
  dinv[node] = d;
  const float* er = emb + (size_t)x_ids[node] * 16;
  float4 e0 = *(const float4*)(er);
  float4 e1 = *(const float4*)(er + 4);
  float4 e2 = *(const float4*)(er + 8);
  float4 e3 = *(const float4*)(er + 12);
  uint4 o0, o1;
  o0.x = pk(e0.x * d, e0.y * d); o0.y = pk(e0.z * d, e0.w * d);
  o0.z = pk(e1.x * d, e1.y * d); o0.w = pk(e1.z * d, e1.w * d);
  o1.x = pk(e2.x * d, e2.y * d); o1.y = pk(e2.z * d, e2.w * d);
  o1.z = pk(e3.x * d, e3.y * d); o1.w = pk(e3.z * d, e3.w * d);
  *(uint4*)(ag1 + (size_t)node * 16) = o0;
  *(uint4*)(ag1 + (size_t)node * 16 + 8) = o1;
}

// layer 1: LDS-local CSR rebuild + register aggregation + fused GEMV/ReLU.
// 512 threads: 2 lanes per node (half = 8 features, uint4 gathers).
__global__ __launch_bounds__(512) void k_fuse1(const unsigned short* __restrict__ ag1,
                                               const int* __restrict__ staging,
                                               const int* __restrict__ bucket_off,
                                               const float* __restrict__ dinv,
                                               const float* __restrict__ W1,
                                               const float* __restrict__ b1, int N,
                                               unsigned short* __restrict__ y1g) {
  __shared__ int list[CAP];
  __shared__ int cnt[BKTN], sc[BKTN], lcur[BKTN];
  __shared__ float W[512];
  __shared__ float bb[32];
  int tid = threadIdx.x, b = blockIdx.x;
  if (tid < 512) W[tid] = W1[tid];
  if (tid < 32) bb[tid] = b1[tid];
  int nloc = tid >> 1, half = tid & 1;
  int node = (b << BSH) + nloc;
  float acc[8];
  if (node < N) {
    uint4 v = *(const uint4*)(ag1 + (size_t)node * 16 + half * 8);
    acc[0] = bf2f(v.x & 0xFFFF); acc[1] = bf2f(v.x >> 16);
    acc[2] = bf2f(v.y & 0xFFFF); acc[3] = bf2f(v.y >> 16);
    acc[4] = bf2f(v.z & 0xFFFF); acc[5] = bf2f(v.z >> 16);
    acc[6] = bf2f(v.w & 0xFFFF); acc[7] = bf2f(v.w >> 16);
  } else {
#pragma unroll
    for (int k = 0; k < 8; ++k) acc[k] = 0.f;
  }
  int beg = bucket_off[b], end = bucket_off[b + 1];
  for (int cbeg = beg; cbeg < end; cbeg += CAP) {
    int cend = min(end, cbeg + CAP);
    if (tid < BKTN) cnt[tid] = 0;
    __syncthreads();
    for (int i = cbeg + tid; i < cend; i += 512)
      atomicAdd(&cnt[staging[i] & (BKTN - 1)], 1);
    __syncthreads();
    if (tid < BKTN) sc[tid] = cnt[tid];
    __syncthreads();
    for (int o = 1; o < BKTN; o <<= 1) {
      int u = (tid < BKTN && tid >= o) ? sc[tid - o] : 0;
      __syncthreads();
      if (tid < BKTN) sc[tid] += u;
      __syncthreads();
    }
    if (tid < BKTN) {
      int st = sc[tid] - cnt[tid];
      sc[tid] = st;
      lcur[tid] = st;
    }
    __syncthreads();
    for (int i = cbeg + tid; i < cend; i += 512) {
      int p = staging[i];
      int pos = atomicAdd(&lcur[p & (BKTN - 1)], 1);
      list[pos] = p >> BSH;
    }
    __syncthreads();
    if (node < N) {
      int st = sc[nloc], dg = cnt[nloc];
      for (int j = 0; j < dg; ++j) {
        int r = list[st + j];
        uint4 v = *(const uint4*)(ag1 + (size_t)r * 16 + half * 8);
        acc[0] += bf2f(v.x & 0xFFFF); acc[1] += bf2f(v.x >> 16);
        acc[2] += bf2f(v.y & 0xFFFF); acc[3] += bf2f(v.y >> 16);
        acc[4] += bf2f(v.z & 0xFFFF); acc[5] += bf2f(v.z >> 16);
        acc[6] += bf2f(v.w & 0xFFFF); acc[7] += bf2f(v.w >> 16);
      }
    }
    __syncthreads();
  }
  if (node >= N) return;
  float d = dinv[node];
  float sx[8], xo[8];
#pragma unroll
  for (int k = 0; k < 8; ++k) sx[k] = acc[k] * d;
#pragma unroll
  for (int k = 0; k < 8; ++k) xo[k] = __shfl_xor(sx[k], 1);
  float x[16];
  if (half == 0) {
#pragma unroll
    for (int k = 0; k < 8; ++k) { x[k] = sx[k]; x[8 + k] = xo[k]; }
  } else {
#pragma unroll
    for (int k = 0; k < 8; ++k) { x[k] = xo[k]; x[8 + k] = sx[k]; }
  }
  int j0 = half * 16;
  float a[16];
#pragma unroll
  for (int j = 0; j < 16; ++j) a[j] = bb[j0 + j];
#pragma unroll
  for (int k = 0; k < 16; ++k) {
    float xv = x[k];
#pragma unroll
    for (int j = 0; j < 16; ++j) a[j] += xv * W[k * 32 + j0 + j];
  }
#pragma unroll
  for (int j = 0; j < 16; ++j) a[j] = fmaxf(a[j], 0.f) * d;
  uint4 o0 = {pk(a[0], a[1]), pk(a[2], a[3]), pk(a[4], a[5]), pk(a[6], a[7])};
  uint4 o1 = {pk(a[8], a[9]), pk(a[10], a[11]), pk(a[12], a[13]), pk(a[14], a[15])};
  unsigned short* yp = y1g + (size_t)half * N * 16 + (size_t)node * 16;
  *(uint4*)(yp) = o0;
  *(uint4*)(yp + 8) = o1;
}

// layer 2, one 16-feat plane: LDS CSR rebuild + register aggregation -> s2 f32
__global__ __launch_bounds__(512) void k_fuse2(const unsigned short* __restrict__ y1p,
                                               const int* __restrict__ staging,
                                               const int* __restrict__ bucket_off,
                                               const float* __restrict__ dinv, int N,
                                               float* __restrict__ s2p) {
  __shared__ int list[CAP];
  __shared__ int cnt[BKTN], sc[BKTN], lcur[BKTN];
  int tid = threadIdx.x, b = blockIdx.x;
  int nloc = tid >> 1, half = tid & 1;
  int node = (b << BSH) + nloc;
  float acc[8];
  if (node < N) {
    uint4 v = *(const uint4*)(y1p + (size_t)node * 16 + half * 8);
    acc[0] = bf2f(v.x & 0xFFFF); acc[1] = bf2f(v.x >> 16);
    acc[2] = bf2f(v.y & 0xFFFF); acc[3] = bf2f(v.y >> 16);
    acc[4] = bf2f(v.z & 0xFFFF); acc[5] = bf2f(v.z >> 16);
    acc[6] = bf2f(v.w & 0xFFFF); acc[7] = bf2f(v.w >> 16);
  } else {
#pragma unroll
    for (int k = 0; k < 8; ++k) acc[k] = 0.f;
  }
  int beg = bucket_off[b], end = bucket_off[b + 1];
  for (int cbeg = beg; cbeg < end; cbeg += CAP) {
    int cend = min(end, cbeg + CAP);
    if (tid < BKTN) cnt[tid] = 0;
    __syncthreads();
    for (int i = cbeg + tid; i < cend; i += 512)
      atomicAdd(&cnt[staging[i] & (BKTN - 1)], 1);
    __syncthreads();
    if (tid < BKTN) sc[tid] = cnt[tid];
    __syncthreads();
    for (int o = 1; o < BKTN; o <<= 1) {
      int u = (tid < BKTN && tid >= o) ? sc[tid - o] : 0;
      __syncthreads();
      if (tid < BKTN) sc[tid] += u;
      __syncthreads();
    }
    if (tid < BKTN) {
      int st = sc[tid] - cnt[tid];
      sc[tid] = st;
      lcur[tid] = st;
    }
    __syncthreads();
    for (int i = cbeg + tid; i < cend; i += 512) {
      int p = staging[i];
      int pos = atomicAdd(&lcur[p & (BKTN - 1)], 1);
      list[pos] = p >> BSH;
    }
    __syncthreads();
    if (node < N) {
      int st = sc[nloc], dg = cnt[nloc];
      for (int j = 0; j < dg; ++j) {
        int r = list[st + j];
        uint4 v = *(const uint4*)(y1p + (size_t)r * 16 + half * 8);
        acc[0] += bf2f(v.x & 0xFFFF); acc[1] += bf2f(v.x >> 16);
        acc[2] += bf2f(v.y & 0xFFFF); acc[3] += bf2f(v.y >> 16);
        acc[4] += bf2f(v.z & 0xFFFF); acc[5] += bf2f(v.z >> 16);
        acc[6] += bf2f(v.w & 0xFFFF); acc[7] += bf2f(v.w >> 16);
      }
    }
    __syncthreads();
  }
  if (node >= N) return;
  float d = dinv[node];
  float4 w0 = {acc[0] * d, acc[1] * d, acc[2] * d, acc[3] * d};
  float4 w1 = {acc[4] * d, acc[5] * d, acc[6] * d, acc[7] * d};
  float* sp = s2p + (size_t)node * 16 + half * 8;
  *(float4*)(sp) = w0;
  *(float4*)(sp + 4) = w1;
}

// batch is SORTED: block g binary-searches its node range, sums s2 rows
// (plane-major layout), then out[g] = psum @ W2 + cnt*b2. No atomics.
__global__ __launch_bounds__(BLK) void k_pool(const float* __restrict__ s2,
                                              const int* __restrict__ batch, int N,
                                              const float* __restrict__ W2,
                                              const float* __restrict__ b2,
                                              float* __restrict__ out) {
  __shared__ int se[2];
  __shared__ float sd[BLK];
  int g = blockIdx.x, tid = threadIdx.x;
  if (tid < 2) {
    int v = g + tid;
    int lo = 0, hi = N;
    while (lo < hi) {
      int mid = (lo + hi) >> 1;
      if (batch[mid] < v) lo = mid + 1; else hi = mid;
    }
    se[tid] = lo;
  }
  __syncthreads();
  int start = se[0], end = se[1];
  int f = tid & 31, grp = tid >> 5;
  const float* base = s2 + (size_t)(f >> 4) * N * 16 + (f & 15);
  float acc = 0.f;
  for (int n = start + grp; n < end; n += 8) acc += base[(size_t)n * 16];
  sd[tid] = acc;
  __syncthreads();
  if (tid < 128) sd[tid] += sd[tid + 128];
  __syncthreads();
  if (tid < 64) sd[tid] += sd[tid + 64];
  __syncthreads();
  if (tid < 32) sd[tid] += sd[tid + 32];
  __syncthreads();
  if (tid < 41) {
    float o = (float)(end - start) * b2[tid];
#pragma unroll
    for (int k = 0; k < 32; ++k) o += sd[k] * W2[k * 41 + tid];
    out[(size_t)g * 41 + tid] = o;
  }
}

extern "C" void kernel_launch(void* const* d_in, const int* in_sizes, int n_in,
                              void* d_out, int out_size, void* d_ws, size_t ws_size,
                              hipStream_t stream) {
  const int* x_ids = (const int*)d_in[0];
  const int* edge_index = (const int*)d_in[1];
  const int* batch = (const int*)d_in[2];
  const float* emb = (const float*)d_in[3];
  const float* W1 = (const float*)d_in[4];
  const float* b1 = (const float*)d_in[5];
  const float* W2 = (const float*)d_in[6];
  const float* b2 = (const float*)d_in[7];
  float* out = (float*)d_out;

  const int N = in_sizes[0];
  const int E = in_sizes[1] / 2;
  const int G = out_size / 41;
  const int* row = edge_index;
  const int* col = edge_index + E;

  const int nbkt = (N + BKTN - 1) >> BSH;       // 391
  const int nblk = (E + EPB - 1) / EPB;         // 391
  const int tot = nbkt * nblk;                  // ~153K
  const int nscan = (tot + 1023) >> 10;         // ~150

  char* ws = (char*)d_ws;
  size_t woff = 0;
  auto alloc = [&](size_t bytes) -> char* {
    char* p = ws + woff;
    woff += (bytes + 255) & ~(size_t)255;
    return p;
  };
  int* staging = (int*)alloc((size_t)E * 4);
  float* dinv = (float*)alloc((size_t)N * 4);
  unsigned short* ag1 = (unsigned short*)alloc((size_t)N * 16 * 2);
  unsigned short* y1g = (unsigned short*)alloc((size_t)N * 32 * 2);
  float* s2 = (float*)alloc((size_t)N * 32 * 4);
  int* hist = (int*)alloc((size_t)tot * 4);
  int* off = (int*)alloc((size_t)tot * 4);
  int* bucket_off = (int*)alloc(((size_t)nbkt + 1) * 4);
  int* bsums = (int*)alloc((size_t)nscan * 4);
  (void)ws_size; (void)n_in;

  k_hist<<<nblk, BLK, 0, stream>>>(col, E, nbkt, nblk, hist);
  k_scan_a<<<nscan, 1024, 0, stream>>>(hist, tot, off, bsums);
  k_scan_c<<<nscan, 1024, 0, stream>>>(tot, nblk, nbkt, E, nscan, bsums, off, bucket_off);
  k_scatter<<<nblk, BLK, 0, stream>>>(row, col, E, nbkt, nblk, off, staging);
  k_degprep<<<nbkt, BLK, 0, stream>>>(staging, bucket_off, x_ids, emb, N, dinv, ag1);
  k_fuse1<<<nbkt, 512, 0, stream>>>(ag1, staging, bucket_off, dinv, W1, b1, N, y1g);
  k_fuse2<<<nbkt, 512, 0, stream>>>(y1g, staging, bucket_off, dinv, N, s2);
  k_fuse2<<<nbkt, 512, 0, stream>>>(y1g + (size_t)N * 16, staging, bucket_off, dinv, N,
                                    s2 + (size_t)N * 16);
  k_pool<<<G, BLK, 0, stream>>>(s2, batch, N, W2, b2, out);
}